// Round 9
// baseline (299.337 us; speedup 1.0000x reference)
//
#include <hip/hip_runtime.h>
#include <hip/hip_bf16.h>
#include <math.h>

#define BSZ 8
#define DDIM 512
#define NND 2048
#define EE 8
#define LLH 64
#define NEDGE 524288
#define BNN 16384          // BSZ*NND
#define OCC 1536           // 3*EE*LLH
#define DQ 16384           // per-third flat d dimension
#define NBLK_EDGES 512

typedef __attribute__((ext_vector_type(8))) short short8;

__device__ inline unsigned short f2bf(float x) {
    __hip_bfloat16 h = __float2bfloat16(x);
    return __builtin_bit_cast(unsigned short, h);
}
__device__ inline float bf2f(unsigned short u) {
    return __uint_as_float(((unsigned int)u) << 16);
}

__device__ inline void gridbar(int* c, int target) {
    __syncthreads();
    if (threadIdx.x == 0) {
        __threadfence();
        atomicAdd(c, 1);
        while (atomicAdd(c, 0) < target) __builtin_amdgcn_s_sleep(32);
        __threadfence();
    }
    __syncthreads();
}

// ==== 1. front: zero bufs + fused dense+conv1+QKV  ||  G precompute ====
// grid 192: x<64 node-blocks (32 nodes x 8 b); x in [64,192) G-blocks (t = (x-64)>>1, s-half)
__global__ __launch_bounds__(256) void k_front(const float* __restrict__ latent,
                                               const float* __restrict__ Wd,
                                               const float* __restrict__ bd,
                                               const float* __restrict__ w1,
                                               const float* __restrict__ b1,
                                               const float* __restrict__ Wq, const float* __restrict__ bq,
                                               const float* __restrict__ Wk, const float* __restrict__ bk,
                                               const float* __restrict__ Wv,
                                               const float* __restrict__ qw,
                                               const float* __restrict__ qb,
                                               float* __restrict__ Qg, float* __restrict__ Kg,
                                               float* __restrict__ Vg,
                                               float* __restrict__ G,
                                               int* __restrict__ hist, int* __restrict__ zcnt,
                                               int* __restrict__ cbar) {
    int bx = blockIdx.x, tid = threadIdx.x;
    if (bx < 64) {
        // ---- zero reduction buffers for k_edges ----
        hist[bx * 256 + tid] = 0;
        zcnt[bx * 256 + tid] = 0;
        if (bx == 0 && tid < 16) cbar[tid] = 0;
        __shared__ float lat[8][512];
        __shared__ float pdl[34][4][8];
        __shared__ float skel[36][8];
        for (int i = tid; i < 4096; i += 256) lat[i >> 9][i & 511] = latent[i];
        __syncthreads();
        int n0 = bx * 32;
        {   // dense partials: thread (nl<34, dq) -> 128-d partial for 8 b
            int nl = tid & 63, dq = tid >> 6;
            if (nl < 34) {
                int n = n0 - 1 + nl;
                float acc[8] = {0.f,0.f,0.f,0.f,0.f,0.f,0.f,0.f};
                if (n >= 0 && n < NND) {
                    const float* wp = Wd + (size_t)dq * 128 * NND + n;
                    for (int d = 0; d < 128; ++d) {
                        float w = wp[(size_t)d * NND];
                        int dd = dq * 128 + d;
                        #pragma unroll
                        for (int b = 0; b < 8; ++b) acc[b] += lat[b][dd] * w;
                    }
                }
                #pragma unroll
                for (int b = 0; b < 8; ++b) pdl[nl][dq][b] = acc[b];
            }
        }
        __syncthreads();
        for (int idx = tid; idx < 34 * 8; idx += 256) {
            int h = idx >> 3, b = idx & 7;
            int n = n0 - 1 + h;
            float s = 0.f;
            if (n >= 0 && n < NND)
                s = pdl[h][0][b] + pdl[h][1][b] + pdl[h][2][b] + pdl[h][3][b] + bd[n];
            skel[h][b] = s;
        }
        __syncthreads();
        {   // conv1 + GAT QKV
            int nl2 = tid >> 3, b = tid & 7;
            int n = n0 + nl2;
            float sm = skel[nl2][b], s0 = skel[nl2 + 1][b], sp = skel[nl2 + 2][b];
            float xr[EE];
            #pragma unroll
            for (int e = 0; e < EE; ++e)
                xr[e] = sm * w1[e] + s0 * w1[EE + e] + sp * w1[2 * EE + e] + b1[e];
            size_t i = (size_t)b * NND + n;
            #pragma unroll
            for (int j = 0; j < EE; ++j) {
                float q = bq[j], k = bk[j], v = 0.f;
                #pragma unroll
                for (int c = 0; c < EE; ++c) {
                    q += xr[c] * Wq[c * EE + j];
                    k += xr[c] * Wk[c * EE + j];
                    v += xr[c] * Wv[c * EE + j];
                }
                Qg[i * EE + j] = (q >= 0.f) ? q : 0.2f * q;
                Kg[i * EE + j] = (k >= 0.f) ? k : 0.2f * k;
                Vg[i * EE + j] = v;
            }
        }
    } else {
        // ---- G precompute: G[((t*2+m)*625+p)*64+s] ----
        int gi = bx - 64;
        int t = gi >> 1, shalf = gi & 1;
        __shared__ float A[25][24];
        for (int idx = tid; idx < 600; idx += 256) {
            int i = idx / 24, c = idx - (idx / 24) * 24;
            A[i][c] = (i < 24) ? qw[i * OCC + t * 24 + c] : qb[t * 24 + c];
        }
        __syncthreads();
        int s = shalf * 32 + (tid & 31), q = tid >> 5;   // q 0..7
        for (int p = q; p < 625; p += 8) {
            int i = p / 25, j = p - (p / 25) * 25;
            float B[24];
            if (j < 24) {
                const float4* bp = (const float4*)(qw + (size_t)j * OCC + s * 24);
                #pragma unroll
                for (int r = 0; r < 6; ++r) {
                    float4 v = bp[r];
                    B[r*4+0]=v.x; B[r*4+1]=v.y; B[r*4+2]=v.z; B[r*4+3]=v.w;
                }
            } else {
                const float4* bp = (const float4*)(qb + s * 24);
                #pragma unroll
                for (int r = 0; r < 6; ++r) {
                    float4 v = bp[r];
                    B[r*4+0]=v.x; B[r*4+1]=v.y; B[r*4+2]=v.z; B[r*4+3]=v.w;
                }
            }
            float g1 = 0.f, g2 = 0.f;
            #pragma unroll
            for (int c = 0; c < 16; ++c) g1 += A[i][c] * B[c + 8];
            #pragma unroll
            for (int c = 16; c < 24; ++c) g2 += A[i][c] * B[c - 16];
            G[((size_t)(t * 2 + 0) * 625 + p) * 64 + s] = g1;
            G[((size_t)(t * 2 + 1) * 625 + p) * 64 + s] = g2;
        }
    }
}

// ==== 2. edges: hist -> bar -> scan(LDS) -> scatter -> bar -> gatagg ====
// 512 blocks x 256 thr; LDS 65.6KB forces exactly 2 blocks/CU => 512 co-resident
__global__ __launch_bounds__(256) void k_edges(const int* __restrict__ ei,
                                               int* __restrict__ hist, int* __restrict__ zcnt,
                                               int* __restrict__ cbar, int* __restrict__ ecol,
                                               const float* __restrict__ Qg,
                                               const float* __restrict__ Kg,
                                               const float* __restrict__ Vg,
                                               const float* __restrict__ gbias,
                                               float* __restrict__ hg) {
    __shared__ int offs[16385];
    __shared__ int wsum[4];
    int bid = blockIdx.x, tid = threadIdx.x;
    int e0 = bid * 1024;
    // phase 1: histogram
    #pragma unroll
    for (int k = 0; k < 4; ++k) atomicAdd(hist + ei[e0 + k * 256 + tid], 1);
    gridbar(cbar + 0, NBLK_EDGES);
    // phase 2: full scan into LDS (redundant per block)
    {
        int base = tid * 64, sum = 0;
        const int4* h4 = (const int4*)(hist + base);
        #pragma unroll
        for (int i = 0; i < 16; ++i) { int4 v = h4[i]; sum += v.x + v.y + v.z + v.w; }
        int lane = tid & 63, wv = tid >> 6;
        int inc = sum;
        #pragma unroll
        for (int off = 1; off < 64; off <<= 1) {
            int u = __shfl_up(inc, off, 64);
            if (lane >= off) inc += u;
        }
        if (lane == 63) wsum[wv] = inc;
        __syncthreads();
        if (tid == 0) {
            int t0 = wsum[0], t1 = wsum[1], t2 = wsum[2];
            wsum[0] = 0; wsum[1] = t0; wsum[2] = t0 + t1; wsum[3] = t0 + t1 + t2;
        }
        __syncthreads();
        int run = wsum[wv] + inc - sum;
        #pragma unroll
        for (int i = 0; i < 16; ++i) {
            int4 v = h4[i];
            offs[base + i*4 + 0] = run; run += v.x;
            offs[base + i*4 + 1] = run; run += v.y;
            offs[base + i*4 + 2] = run; run += v.z;
            offs[base + i*4 + 3] = run; run += v.w;
        }
        if (tid == 0) offs[16384] = NEDGE;
    }
    __syncthreads();
    // phase 3: scatter
    #pragma unroll
    for (int k = 0; k < 4; ++k) {
        int e = e0 + k * 256 + tid;
        int r = ei[e], c = ei[NEDGE + e];
        int pos = offs[r] + atomicAdd(zcnt + r, 1);
        ecol[pos] = c;
    }
    gridbar(cbar + 1, NBLK_EDGES);
    // phase 4: gatagg — wave per row, 8 rows per wave
    int lane = tid & 63;
    int wid = bid * 4 + (tid >> 6);
    for (int k = 0; k < 8; ++k) {
        int row = __builtin_amdgcn_readfirstlane(wid + k * 2048);
        int beg = offs[row];
        int deg = offs[row + 1] - beg;
        const float* Qr = Qg + (size_t)row * EE;
        float q0 = Qr[0], q1 = Qr[1], q2 = Qr[2], q3 = Qr[3];
        float q4 = Qr[4], q5 = Qr[5], q6 = Qr[6], q7 = Qr[7];
        int total = deg + 1;
        float m = -INFINITY, l = 0.f;
        float acc[EE];
        #pragma unroll
        for (int j = 0; j < EE; ++j) acc[j] = 0.f;
        for (int base = 0; base < total; base += 64) {
            int idx = base + lane;
            int c = row;
            if (idx < deg) c = ecol[beg + idx];
            const float4* K4 = (const float4*)(Kg + (size_t)c * EE);
            float4 ka = K4[0], kb = K4[1];
            float s = q0*ka.x + q1*ka.y + q2*ka.z + q3*ka.w
                    + q4*kb.x + q5*kb.y + q6*kb.z + q7*kb.w;
            if (idx >= total) s = -INFINITY;
            float pm = s;
            #pragma unroll
            for (int off = 32; off > 0; off >>= 1) pm = fmaxf(pm, __shfl_xor(pm, off));
            float nm = fmaxf(m, pm);
            float scale = __expf(m - nm);
            float p = (idx < total) ? __expf(s - nm) : 0.f;
            float ps = p;
            #pragma unroll
            for (int off = 32; off > 0; off >>= 1) ps += __shfl_xor(ps, off);
            l = l * scale + ps;
            const float4* V4 = (const float4*)(Vg + (size_t)c * EE);
            float4 va = V4[0], vb = V4[1];
            float pv[EE] = {p*va.x, p*va.y, p*va.z, p*va.w, p*vb.x, p*vb.y, p*vb.z, p*vb.w};
            #pragma unroll
            for (int j = 0; j < EE; ++j) {
                float t = pv[j];
                #pragma unroll
                for (int off = 32; off > 0; off >>= 1) t += __shfl_xor(t, off);
                acc[j] = acc[j] * scale + t;
            }
            m = nm;
        }
        if (lane < EE)
            hg[(size_t)row * EE + lane] = acc[lane] / l + gbias[lane];
    }
}

// ==== 3. v-third conv -> Fq bf16 rows 682..1365  ||  Mpart blocks ====
// grid (30, 8): x<22 conv chunks; x>=22 -> M split (x-22)
__global__ __launch_bounds__(256) void k_qkvFvM(const float* __restrict__ hg,
                                                const float* __restrict__ qw,
                                                const float* __restrict__ qb,
                                                unsigned short* __restrict__ Fq,
                                                float* __restrict__ Mpart) {
    int bx = blockIdx.x, b = blockIdx.y, tid = threadIdx.x;
    if (bx < 22) {
        int n0 = 682 + bx * 32;
        __shared__ float hs[34 * EE];
        __shared__ unsigned short st[32 * 768];
        for (int i = tid; i < 34 * EE; i += 256) {
            int nn = n0 - 1 + (i >> 3);
            hs[i] = (nn >= 0 && nn < NND) ? hg[((size_t)b * NND + nn) * EE + (i & 7)] : 0.f;
        }
        __syncthreads();
        #pragma unroll
        for (int pass = 0; pass < 2; ++pass) {
            if (pass) __syncthreads();
            float w[3][24], bias[3];
            #pragma unroll
            for (int rr = 0; rr < 3; ++rr) {
                int o = pass * 768 + rr * 256 + tid;
                bias[rr] = qb[o];
                #pragma unroll
                for (int kk = 0; kk < 24; ++kk) w[rr][kk] = qw[kk * OCC + o];
            }
            for (int nn = 0; nn < 32; ++nn) {
                const float* hv = &hs[nn * EE];
                float a0 = bias[0], a1 = bias[1], a2 = bias[2];
                #pragma unroll
                for (int kk = 0; kk < 24; ++kk) {
                    float h = hv[kk];
                    a0 += h * w[0][kk]; a1 += h * w[1][kk]; a2 += h * w[2][kk];
                }
                st[nn * 768 + tid]       = f2bf(a0);
                st[nn * 768 + tid + 256] = f2bf(a1);
                st[nn * 768 + tid + 512] = f2bf(a2);
            }
            __syncthreads();
            unsigned short* dstbase = Fq + ((size_t)b * NND + n0) * OCC + pass * 768;
            #pragma unroll
            for (int it = 0; it < 12; ++it) {
                int idx8 = it * 256 + tid;
                int row = idx8 / 96, col8 = idx8 - row * 96;
                if (n0 + row <= 1365)
                    *(short8*)(dstbase + (size_t)row * OCC + col8 * 8) =
                        *(const short8*)(&st[row * 768 + col8 * 8]);
            }
        }
    } else {
        // M split: M1[i,j] = sum_n hwin[n][i]*hwin[n+1365][j] (n 0..682)
        //          M2[i,j] = sum_n hwin[n][i]*hwin[n+1366][j] (n 0..681)
        int sp = bx - 22;
        int nq0 = sp * 86;
        __shared__ float hq[88][EE];
        __shared__ float hk[90][EE];
        for (int i = tid; i < 88 * EE; i += 256) {
            int r = nq0 - 1 + (i >> 3);
            hq[i >> 3][i & 7] = (r >= 0 && r < NND) ? hg[((size_t)b * NND + r) * EE + (i & 7)] : 0.f;
        }
        for (int i = tid; i < 90 * EE; i += 256) {
            int r = nq0 + 1364 + (i >> 3);
            hk[i >> 3][i & 7] = (r < NND) ? hg[((size_t)b * NND + r) * EE + (i & 7)] : 0.f;
        }
        __syncthreads();
        int cnt1 = 683 - nq0; if (cnt1 > 86) cnt1 = 86; if (cnt1 < 0) cnt1 = 0;
        int cnt2 = 682 - nq0; if (cnt2 > 86) cnt2 = 86; if (cnt2 < 0) cnt2 = 0;
        for (int idx = tid; idx < 1250; idx += 256) {
            int mm = idx / 625, p = idx - (idx / 625) * 625;
            int i = p / 25, j = p - (p / 25) * 25;
            int cnt = mm ? cnt2 : cnt1;
            int qi = i >> 3, qe = i & 7;
            int kj = (j >> 3) + mm, ke = j & 7;
            float acc = 0.f;
            if (i < 24 && j < 24) {
                for (int nl = 0; nl < cnt; ++nl)
                    acc += hq[nl + qi][qe] * hk[nl + kj][ke];
            } else if (i < 24) {         // j == 24
                for (int nl = 0; nl < cnt; ++nl) acc += hq[nl + qi][qe];
            } else if (j < 24) {         // i == 24
                for (int nl = 0; nl < cnt; ++nl) acc += hk[nl + kj][ke];
            } else {
                acc = (float)cnt;
            }
            Mpart[((size_t)(sp * 8 + b)) * 1250 + idx] = acc;
        }
    }
}

// ==== 4. S = G x M, softmax -> atT[b][s][t] ====  (64 blocks, one per t)
__global__ __launch_bounds__(256) void k_Ssm(const float* __restrict__ G,
                                             const float* __restrict__ Mpart,
                                             float* __restrict__ atT) {
    __shared__ float Ms[8][1250];
    int t = blockIdx.x, tid = threadIdx.x;
    for (int idx = tid; idx < 10000; idx += 256) {
        int b = idx / 1250, r = idx - (idx / 1250) * 1250;
        float s = 0.f;
        #pragma unroll
        for (int sp = 0; sp < 8; ++sp)
            s += Mpart[((size_t)(sp * 8 + b)) * 1250 + r];
        Ms[b][r] = s;
    }
    __syncthreads();
    int s = tid & 63, bg = tid >> 6;
    const float* Gt = G + (size_t)t * 1250 * 64;
    float acc0 = 0.f, acc1 = 0.f;
    for (int u = 0; u < 625; ++u) {
        float g1 = Gt[(size_t)u * 64 + s];
        float g2 = Gt[(size_t)(625 + u) * 64 + s];
        acc0 += g1 * Ms[bg][u] + g2 * Ms[bg][625 + u];
        acc1 += g1 * Ms[bg + 4][u] + g2 * Ms[bg + 4][625 + u];
    }
    #pragma unroll
    for (int r = 0; r < 2; ++r) {
        int b = bg + r * 4;
        float v = r ? acc1 : acc0;
        float m = v;
        #pragma unroll
        for (int off = 32; off > 0; off >>= 1) m = fmaxf(m, __shfl_xor(m, off));
        float e = __expf(v - m);
        float sum = e;
        #pragma unroll
        for (int off = 32; off > 0; off >>= 1) sum += __shfl_xor(sum, off);
        atT[((size_t)b * LLH + s) * LLH + t] = e / sum;
    }
}

// ==== 5. out[b][t][d] = sum_s atT[b][s][t] * v[s][d]; v staged in LDS ====
__global__ __launch_bounds__(256) void k_attnV(const unsigned short* __restrict__ Fq,
                                               const float* __restrict__ atT,
                                               float* __restrict__ out) {
    int b = blockIdx.y;
    int d0 = blockIdx.x * 64;
    int tid = threadIdx.x;
    __shared__ unsigned short vt[64 * 64];
    const unsigned short* Fb = Fq + (size_t)b * NND * OCC;
    #pragma unroll
    for (int r = 0; r < 16; ++r) {
        int idx = r * 256 + tid;
        int s = idx >> 6, d = idx & 63;
        int f = DQ + d0 + d;
        int n = f / 24, c = f - n * 24;
        vt[s * 64 + d] = Fb[(size_t)n * OCC + s * 24 + c];
    }
    __syncthreads();
    int lane = tid & 63;
    int t0 = __builtin_amdgcn_readfirstlane((tid >> 6) * 16);
    const float* arow = atT + (size_t)b * LLH * LLH + t0;
    float acc[16];
    #pragma unroll
    for (int tt = 0; tt < 16; ++tt) acc[tt] = 0.f;
    #pragma unroll 4
    for (int s = 0; s < LLH; ++s) {
        float vv = bf2f(vt[s * 64 + lane]);
        #pragma unroll
        for (int tt = 0; tt < 16; ++tt)
            acc[tt] += arow[s * LLH + tt] * vv;
    }
    float* ob = out + ((size_t)b * LLH + t0) * DQ + d0 + lane;
    #pragma unroll
    for (int tt = 0; tt < 16; ++tt) ob[(size_t)tt * DQ] = acc[tt];
}

extern "C" void kernel_launch(void* const* d_in, const int* in_sizes, int n_in,
                              void* d_out, int out_size, void* d_ws, size_t ws_size,
                              hipStream_t stream) {
    (void)in_sizes; (void)n_in; (void)out_size; (void)ws_size;
    const float* latent = (const float*)d_in[0];
    const int*   ei     = (const int*)d_in[1];
    const float* Wd     = (const float*)d_in[2];
    const float* bd     = (const float*)d_in[3];
    const float* w1     = (const float*)d_in[4];
    const float* b1     = (const float*)d_in[5];
    const float* Wq     = (const float*)d_in[6];
    const float* bq     = (const float*)d_in[7];
    const float* Wk     = (const float*)d_in[8];
    const float* bk     = (const float*)d_in[9];
    const float* Wv     = (const float*)d_in[10];
    const float* gbias  = (const float*)d_in[11];
    const float* qw     = (const float*)d_in[12];
    const float* qb     = (const float*)d_in[13];
    float* out = (float*)d_out;

    float* ws   = (float*)d_ws;
    float* Qg   = ws;                            // 131072
    float* Kg   = Qg + BNN * EE;                 // 131072
    float* Vg   = Kg + BNN * EE;                 // 131072
    float* hg   = Vg + BNN * EE;                 // 131072
    float* G    = hg + BNN * EE;                 // 64*1250*64 = 5,120,000
    float* Mp   = G + (size_t)64 * 1250 * 64;    // 8*8*1250 = 80,000
    float* atT  = Mp + 80000;                    // 32768
    int*   hist = (int*)(atT + BSZ * LLH * LLH); // 16384
    int*   zcnt = hist + BNN;                    // 16384
    int*   cbar = zcnt + BNN;                    // 16
    int*   ecol = cbar + 16;                     // 524288
    unsigned short* Fq = (unsigned short*)(ecol + NEDGE);  // 25,165,824 bf16

    k_front<<<dim3(192), dim3(256), 0, stream>>>(latent, Wd, bd, w1, b1,
                                                 Wq, bq, Wk, bk, Wv, qw, qb,
                                                 Qg, Kg, Vg, G, hist, zcnt, cbar);
    k_edges<<<dim3(NBLK_EDGES), dim3(256), 0, stream>>>(ei, hist, zcnt, cbar, ecol,
                                                        Qg, Kg, Vg, gbias, hg);
    k_qkvFvM<<<dim3(30, 8), dim3(256), 0, stream>>>(hg, qw, qb, Fq, Mp);
    k_Ssm<<<dim3(64), dim3(256), 0, stream>>>(G, Mp, atT);
    k_attnV<<<dim3(256, 8), dim3(256), 0, stream>>>(Fq, atT, out);
}

// Round 10
// 148.178 us; speedup vs baseline: 2.0201x; 2.0201x over previous
//
#include <hip/hip_runtime.h>
#include <hip/hip_bf16.h>
#include <math.h>

#define BSZ 8
#define DDIM 512
#define NND 2048
#define EE 8
#define LLH 64
#define NEDGE 524288
#define BNN 16384          // BSZ*NND
#define OCC 1536           // 3*EE*LLH
#define DQ 16384           // per-third flat d dimension

typedef __attribute__((ext_vector_type(8))) short short8;

__device__ inline unsigned short f2bf(float x) {
    __hip_bfloat16 h = __float2bfloat16(x);
    return __builtin_bit_cast(unsigned short, h);
}
__device__ inline float bf2f(unsigned short u) {
    return __uint_as_float(((unsigned int)u) << 16);
}

// ---- 1. dense partials + zero hist ----
__global__ __launch_bounds__(256) void k_densep(const float* __restrict__ latent,
                                                const float* __restrict__ Wd,
                                                float* __restrict__ pdense,
                                                int* __restrict__ hist) {
    int n0 = blockIdx.x * 32, d0 = blockIdx.y * 64;
    __shared__ float lat[8][64];
    int tid = threadIdx.x;
    if (blockIdx.y == 0) hist[blockIdx.x * 256 + tid] = 0;
    #pragma unroll
    for (int r = 0; r < 2; ++r) {
        int i = r * 256 + tid;
        lat[i >> 6][i & 63] = latent[(i >> 6) * DDIM + d0 + (i & 63)];
    }
    __syncthreads();
    int nl = tid & 31, b = tid >> 5;
    const float* wp = Wd + (size_t)d0 * NND + n0 + nl;
    float acc = 0.f;
    #pragma unroll 8
    for (int d = 0; d < 64; ++d) acc += lat[b][d] * wp[(size_t)d * NND];
    pdense[((size_t)blockIdx.y * BSZ + b) * NND + n0 + nl] = acc;
}

// ---- 2. fused: reduce partials -> conv1 -> GAT QKV projections + edge hist ----
__global__ __launch_bounds__(64) void k_gat(const float* __restrict__ pdense,
                                            const float* __restrict__ bd,
                                            const float* __restrict__ w1,
                                            const float* __restrict__ b1,
                                            const float* __restrict__ Wq, const float* __restrict__ bq,
                                            const float* __restrict__ Wk, const float* __restrict__ bk,
                                            const float* __restrict__ Wv,
                                            const int* __restrict__ ei,
                                            float* __restrict__ Qg, float* __restrict__ Kg,
                                            float* __restrict__ Vg, int* __restrict__ hist) {
    int i = blockIdx.x * 64 + threadIdx.x;
    int b = i >> 11, n = i & (NND - 1);
    float sm = 0.f, s0 = 0.f, sp = 0.f;
    #pragma unroll
    for (int ds = 0; ds < 8; ++ds) {
        const float* p = pdense + ((size_t)ds * BSZ + b) * NND + n;
        if (n > 0) sm += p[-1];
        s0 += p[0];
        if (n < NND - 1) sp += p[1];
    }
    if (n > 0) sm += bd[n - 1];
    s0 += bd[n];
    if (n < NND - 1) sp += bd[n + 1];
    float xr[EE];
    #pragma unroll
    for (int e = 0; e < EE; ++e)
        xr[e] = sm * w1[e] + s0 * w1[EE + e] + sp * w1[2 * EE + e] + b1[e];
    #pragma unroll
    for (int j = 0; j < EE; ++j) {
        float q = bq[j], k = bk[j], v = 0.f;
        #pragma unroll
        for (int c = 0; c < EE; ++c) {
            q += xr[c] * Wq[c * EE + j];
            k += xr[c] * Wk[c * EE + j];
            v += xr[c] * Wv[c * EE + j];
        }
        Qg[(size_t)i * EE + j] = (q >= 0.f) ? q : 0.2f * q;
        Kg[(size_t)i * EE + j] = (k >= 0.f) ? k : 0.2f * k;
        Vg[(size_t)i * EE + j] = v;
    }
    // edge histogram: coalesced grid-stride
    #pragma unroll 4
    for (int j = 0; j < 32; ++j)
        atomicAdd(hist + ei[i + j * BNN], 1);
}

// ---- 3. exclusive prefix sum over 16384 counts ----
__global__ __launch_bounds__(1024) void k_scan(const int* __restrict__ hist,
                                               int* __restrict__ offs,
                                               int* __restrict__ cnt) {
    int tid = threadIdx.x;
    int lane = tid & 63, wv = tid >> 6;
    const int4* hp = (const int4*)(hist + tid * 16);
    int4 a = hp[0], b4 = hp[1], c4 = hp[2], d4 = hp[3];
    int h[16] = {a.x, a.y, a.z, a.w, b4.x, b4.y, b4.z, b4.w,
                 c4.x, c4.y, c4.z, c4.w, d4.x, d4.y, d4.z, d4.w};
    int mysum = 0;
    #pragma unroll
    for (int i = 0; i < 16; ++i) mysum += h[i];
    int inc = mysum;
    #pragma unroll
    for (int off = 1; off < 64; off <<= 1) {
        int u = __shfl_up(inc, off, 64);
        if (lane >= off) inc += u;
    }
    __shared__ int wtot[16];
    if (lane == 63) wtot[wv] = inc;
    __syncthreads();
    if (tid < 16) {
        int t = wtot[tid];
        #pragma unroll
        for (int off = 1; off < 16; off <<= 1) {
            int u = __shfl_up(t, off, 16);
            if (tid >= off) t += u;
        }
        wtot[tid] = t;
    }
    __syncthreads();
    int run = (wv ? wtot[wv - 1] : 0) + inc - mysum;
    #pragma unroll
    for (int i = 0; i < 16; ++i) {
        offs[tid * 16 + i] = run;
        cnt[tid * 16 + i] = run;
        run += h[i];
    }
}

// ---- 4. scatter edge columns into destination buckets ----
__global__ void k_scatter(const int* __restrict__ ei, int* __restrict__ cnt,
                          int* __restrict__ ecol) {
    int e = blockIdx.x * 256 + threadIdx.x;
    if (e >= NEDGE) return;
    int r = ei[e], c = ei[NEDGE + e];
    int pos = atomicAdd(cnt + r, 1);
    ecol[pos] = c;
}

// ---- 5. per-row gather + online softmax + aggregate ----
__global__ __launch_bounds__(256) void k_gatagg(const int* __restrict__ ecol,
                                                const int* __restrict__ offs,
                                                const int* __restrict__ hist,
                                                const float* __restrict__ Qg,
                                                const float* __restrict__ Kg,
                                                const float* __restrict__ Vg,
                                                const float* __restrict__ gbias,
                                                float* __restrict__ hg) {
    int row = __builtin_amdgcn_readfirstlane(blockIdx.x * 4 + (threadIdx.x >> 6));
    int lane = threadIdx.x & 63;
    const float* Qr = Qg + (size_t)row * EE;     // wave-uniform -> scalar loads
    float q0 = Qr[0], q1 = Qr[1], q2 = Qr[2], q3 = Qr[3];
    float q4 = Qr[4], q5 = Qr[5], q6 = Qr[6], q7 = Qr[7];
    int beg = offs[row], deg = hist[row];
    int total = deg + 1;                         // + self-loop
    float m = -INFINITY, l = 0.f;
    float acc[EE];
    #pragma unroll
    for (int j = 0; j < EE; ++j) acc[j] = 0.f;
    for (int base = 0; base < total; base += 64) {
        int idx = base + lane;
        int c = row;
        if (idx < deg) c = ecol[beg + idx];
        const float4* K4 = (const float4*)(Kg + (size_t)c * EE);
        float4 ka = K4[0], kb = K4[1];
        float s = q0*ka.x + q1*ka.y + q2*ka.z + q3*ka.w
                + q4*kb.x + q5*kb.y + q6*kb.z + q7*kb.w;
        if (idx >= total) s = -INFINITY;
        float pm = s;
        #pragma unroll
        for (int off = 32; off > 0; off >>= 1) pm = fmaxf(pm, __shfl_xor(pm, off));
        float nm = fmaxf(m, pm);
        float scale = __expf(m - nm);
        float p = (idx < total) ? __expf(s - nm) : 0.f;
        float ps = p;
        #pragma unroll
        for (int off = 32; off > 0; off >>= 1) ps += __shfl_xor(ps, off);
        l = l * scale + ps;
        const float4* V4 = (const float4*)(Vg + (size_t)c * EE);
        float4 va = V4[0], vb = V4[1];
        float pv[EE] = {p*va.x, p*va.y, p*va.z, p*va.w, p*vb.x, p*vb.y, p*vb.z, p*vb.w};
        #pragma unroll
        for (int j = 0; j < EE; ++j) {
            float t = pv[j];
            #pragma unroll
            for (int off = 32; off > 0; off >>= 1) t += __shfl_xor(t, off);
            acc[j] = acc[j] * scale + t;
        }
        m = nm;
    }
    if (lane < EE)
        hg[(size_t)row * EE + lane] = acc[lane] / l + gbias[lane];
}

// ---- 6. v-third conv -> Fq bf16 rows 682..1365  ||  Mpart blocks ----
// grid (30, 8): x<22 conv chunks; x>=22 -> M split (x-22)
__global__ __launch_bounds__(256) void k_qkvFvM(const float* __restrict__ hg,
                                                const float* __restrict__ qw,
                                                const float* __restrict__ qb,
                                                unsigned short* __restrict__ Fq,
                                                float* __restrict__ Mpart) {
    int bx = blockIdx.x, b = blockIdx.y, tid = threadIdx.x;
    if (bx < 22) {
        int n0 = 682 + bx * 32;
        __shared__ float hs[34 * EE];
        __shared__ unsigned short st[32 * 768];
        for (int i = tid; i < 34 * EE; i += 256) {
            int nn = n0 - 1 + (i >> 3);
            hs[i] = (nn >= 0 && nn < NND) ? hg[((size_t)b * NND + nn) * EE + (i & 7)] : 0.f;
        }
        __syncthreads();
        #pragma unroll
        for (int pass = 0; pass < 2; ++pass) {
            if (pass) __syncthreads();
            float w[3][24], bias[3];
            #pragma unroll
            for (int rr = 0; rr < 3; ++rr) {
                int o = pass * 768 + rr * 256 + tid;
                bias[rr] = qb[o];
                #pragma unroll
                for (int kk = 0; kk < 24; ++kk) w[rr][kk] = qw[kk * OCC + o];
            }
            for (int nn = 0; nn < 32; ++nn) {
                const float* hv = &hs[nn * EE];
                float a0 = bias[0], a1 = bias[1], a2 = bias[2];
                #pragma unroll
                for (int kk = 0; kk < 24; ++kk) {
                    float h = hv[kk];
                    a0 += h * w[0][kk]; a1 += h * w[1][kk]; a2 += h * w[2][kk];
                }
                st[nn * 768 + tid]       = f2bf(a0);
                st[nn * 768 + tid + 256] = f2bf(a1);
                st[nn * 768 + tid + 512] = f2bf(a2);
            }
            __syncthreads();
            unsigned short* dstbase = Fq + ((size_t)b * NND + n0) * OCC + pass * 768;
            #pragma unroll
            for (int it = 0; it < 12; ++it) {
                int idx8 = it * 256 + tid;
                int row = idx8 / 96, col8 = idx8 - row * 96;
                if (n0 + row <= 1365)
                    *(short8*)(dstbase + (size_t)row * OCC + col8 * 8) =
                        *(const short8*)(&st[row * 768 + col8 * 8]);
            }
        }
    } else {
        // Mpart[sp*8+b][m*625 + i*25 + j]
        int sp = bx - 22;
        int nq0 = sp * 86;
        __shared__ float hq[88][EE];
        __shared__ float hk[90][EE];
        for (int i = tid; i < 88 * EE; i += 256) {
            int r = nq0 - 1 + (i >> 3);
            hq[i >> 3][i & 7] = (r >= 0 && r < NND) ? hg[((size_t)b * NND + r) * EE + (i & 7)] : 0.f;
        }
        for (int i = tid; i < 90 * EE; i += 256) {
            int r = nq0 + 1364 + (i >> 3);
            hk[i >> 3][i & 7] = (r < NND) ? hg[((size_t)b * NND + r) * EE + (i & 7)] : 0.f;
        }
        __syncthreads();
        int cnt1 = 683 - nq0; if (cnt1 > 86) cnt1 = 86; if (cnt1 < 0) cnt1 = 0;
        int cnt2 = 682 - nq0; if (cnt2 > 86) cnt2 = 86; if (cnt2 < 0) cnt2 = 0;
        for (int idx = tid; idx < 1250; idx += 256) {
            int mm = idx / 625, p = idx - (idx / 625) * 625;
            int i = p / 25, j = p - (p / 25) * 25;
            int cnt = mm ? cnt2 : cnt1;
            int qi = i >> 3, qe = i & 7;
            int kj = (j >> 3) + mm, ke = j & 7;
            float acc = 0.f;
            if (i < 24 && j < 24) {
                for (int nl = 0; nl < cnt; ++nl)
                    acc += hq[nl + qi][qe] * hk[nl + kj][ke];
            } else if (i < 24) {
                for (int nl = 0; nl < cnt; ++nl) acc += hq[nl + qi][qe];
            } else if (j < 24) {
                for (int nl = 0; nl < cnt; ++nl) acc += hk[nl + kj][ke];
            } else {
                acc = (float)cnt;
            }
            Mpart[((size_t)(sp * 8 + b)) * 1250 + idx] = acc;
        }
    }
}

// ==== 7. S via T1 re-association + softmax -> atT ====  (64 blocks, one per t)
// T1[b][j][c] = sum_i M[b][m(c)][i][j] * A[i][t*24+c];  m=0 for c<16, 1 for c>=16
// S[b,t,s] = sum_j { sum_{c<16} T1*Bj[s*24+8+c] + sum_{c>=16} T1*Bj[s*24+c-16] }
__global__ __launch_bounds__(256) void k_Ssm(const float* __restrict__ qw,
                                             const float* __restrict__ qb,
                                             const float* __restrict__ Mpart,
                                             float* __restrict__ atT) {
    __shared__ float Ms[8][1250];
    __shared__ float As[25 * 24];
    __shared__ float T1[8][25 * 24];
    int t = blockIdx.x, tid = threadIdx.x;
    for (int idx = tid; idx < 10000; idx += 256) {
        int b = idx / 1250, r = idx - (idx / 1250) * 1250;
        float s = 0.f;
        #pragma unroll
        for (int sp = 0; sp < 8; ++sp)
            s += Mpart[((size_t)(sp * 8 + b)) * 1250 + r];
        Ms[b][r] = s;
    }
    for (int idx = tid; idx < 600; idx += 256) {
        int i = idx / 24, c = idx - (idx / 24) * 24;
        As[idx] = (i < 24) ? qw[i * OCC + t * 24 + c] : qb[t * 24 + c];
    }
    __syncthreads();
    for (int idx = tid; idx < 4800; idx += 256) {
        int b = idx / 600, rem = idx - (idx / 600) * 600;
        int j = rem / 24, c = rem - (rem / 24) * 24;
        int mo = (c < 16) ? 0 : 625;
        float acc = 0.f;
        #pragma unroll 5
        for (int i = 0; i < 25; ++i)
            acc += Ms[b][mo + i * 25 + j] * As[i * 24 + c];
        T1[b][j * 24 + c] = acc;
    }
    __syncthreads();
    int s = tid & 63, bg = tid >> 6;
    float acc0 = 0.f, acc1 = 0.f;
    for (int j = 0; j < 25; ++j) {
        float Bv[24];
        const float* bp = (j < 24) ? (qw + (size_t)j * OCC + s * 24) : (qb + s * 24);
        #pragma unroll
        for (int r = 0; r < 6; ++r) {
            float4 v = *(const float4*)(bp + r * 4);
            Bv[r*4+0]=v.x; Bv[r*4+1]=v.y; Bv[r*4+2]=v.z; Bv[r*4+3]=v.w;
        }
        const float* t1a = &T1[bg][j * 24];
        const float* t1b = &T1[bg + 4][j * 24];
        #pragma unroll
        for (int c = 0; c < 16; ++c) {
            acc0 += t1a[c] * Bv[8 + c];
            acc1 += t1b[c] * Bv[8 + c];
        }
        #pragma unroll
        for (int c = 16; c < 24; ++c) {
            acc0 += t1a[c] * Bv[c - 16];
            acc1 += t1b[c] * Bv[c - 16];
        }
    }
    #pragma unroll
    for (int r = 0; r < 2; ++r) {
        int b = bg + r * 4;
        float v = r ? acc1 : acc0;
        float m = v;
        #pragma unroll
        for (int off = 32; off > 0; off >>= 1) m = fmaxf(m, __shfl_xor(m, off));
        float e = __expf(v - m);
        float sum = e;
        #pragma unroll
        for (int off = 32; off > 0; off >>= 1) sum += __shfl_xor(sum, off);
        atT[((size_t)b * LLH + s) * LLH + t] = e / sum;
    }
}

// ---- 8. out[b][t][d] = sum_s atT[b][s][t] * v[s][d]; v staged in LDS ----
__global__ __launch_bounds__(256) void k_attnV(const unsigned short* __restrict__ Fq,
                                               const float* __restrict__ atT,
                                               float* __restrict__ out) {
    int b = blockIdx.y;
    int d0 = blockIdx.x * 64;
    int tid = threadIdx.x;
    __shared__ unsigned short vt[64 * 64];
    const unsigned short* Fb = Fq + (size_t)b * NND * OCC;
    #pragma unroll
    for (int r = 0; r < 16; ++r) {
        int idx = r * 256 + tid;
        int s = idx >> 6, d = idx & 63;
        int f = DQ + d0 + d;
        int n = f / 24, c = f - n * 24;
        vt[s * 64 + d] = Fb[(size_t)n * OCC + s * 24 + c];
    }
    __syncthreads();
    int lane = tid & 63;
    int t0 = __builtin_amdgcn_readfirstlane((tid >> 6) * 16);
    const float* arow = atT + (size_t)b * LLH * LLH + t0;
    float acc[16];
    #pragma unroll
    for (int tt = 0; tt < 16; ++tt) acc[tt] = 0.f;
    #pragma unroll 4
    for (int s = 0; s < LLH; ++s) {
        float vv = bf2f(vt[s * 64 + lane]);
        #pragma unroll
        for (int tt = 0; tt < 16; ++tt)
            acc[tt] += arow[s * LLH + tt] * vv;
    }
    float* ob = out + ((size_t)b * LLH + t0) * DQ + d0 + lane;
    #pragma unroll
    for (int tt = 0; tt < 16; ++tt) ob[(size_t)tt * DQ] = acc[tt];
}

extern "C" void kernel_launch(void* const* d_in, const int* in_sizes, int n_in,
                              void* d_out, int out_size, void* d_ws, size_t ws_size,
                              hipStream_t stream) {
    (void)in_sizes; (void)n_in; (void)out_size; (void)ws_size;
    const float* latent = (const float*)d_in[0];
    const int*   ei     = (const int*)d_in[1];
    const float* Wd     = (const float*)d_in[2];
    const float* bd     = (const float*)d_in[3];
    const float* w1     = (const float*)d_in[4];
    const float* b1     = (const float*)d_in[5];
    const float* Wq     = (const float*)d_in[6];
    const float* bq     = (const float*)d_in[7];
    const float* Wk     = (const float*)d_in[8];
    const float* bk     = (const float*)d_in[9];
    const float* Wv     = (const float*)d_in[10];
    const float* gbias  = (const float*)d_in[11];
    const float* qw     = (const float*)d_in[12];
    const float* qb     = (const float*)d_in[13];
    float* out = (float*)d_out;

    float* ws     = (float*)d_ws;
    float* pdense = ws;                          // 131072
    float* Qg     = pdense + 64 * NND;           // 131072
    float* Kg     = Qg + BNN * EE;               // 131072
    float* Vg     = Kg + BNN * EE;               // 131072
    float* hg     = Vg + BNN * EE;               // 131072
    int*   hist   = (int*)(hg + BNN * EE);       // 16384
    int*   offs   = hist + BNN;                  // 16384
    int*   cnt    = offs + BNN;                  // 16384
    int*   ecol   = cnt + BNN;                   // 524288
    float* Mp     = (float*)(ecol + NEDGE);      // 64*1250 = 80000
    float* atT    = Mp + 80000;                  // 32768
    unsigned short* Fq = (unsigned short*)(atT + BSZ * LLH * LLH);  // 25165824 bf16

    k_densep<<<dim3(64, 8), dim3(256), 0, stream>>>(latent, Wd, pdense, hist);
    k_gat<<<dim3(256), dim3(64), 0, stream>>>(pdense, bd, w1, b1, Wq, bq, Wk, bk, Wv,
                                              ei, Qg, Kg, Vg, hist);
    k_scan<<<dim3(1), dim3(1024), 0, stream>>>(hist, offs, cnt);
    k_scatter<<<dim3(NEDGE / 256), dim3(256), 0, stream>>>(ei, cnt, ecol);
    k_gatagg<<<dim3(BNN / 4), dim3(256), 0, stream>>>(ecol, offs, hist,
                                                      Qg, Kg, Vg, gbias, hg);
    k_qkvFvM<<<dim3(30, 8), dim3(256), 0, stream>>>(hg, qw, qb, Fq, Mp);
    k_Ssm<<<dim3(64), dim3(256), 0, stream>>>(qw, qb, Mp, atT);
    k_attnV<<<dim3(256, 8), dim3(256), 0, stream>>>(Fq, atT, out);
}

// Round 12
// 147.347 us; speedup vs baseline: 2.0315x; 1.0056x over previous
//
#include <hip/hip_runtime.h>
#include <hip/hip_bf16.h>
#include <math.h>

#define BSZ 8
#define DDIM 512
#define NND 2048
#define EE 8
#define LLH 64
#define NEDGE 524288
#define BNN 16384          // BSZ*NND
#define OCC 1536           // 3*EE*LLH
#define DQ 16384           // per-third flat d dimension

typedef __attribute__((ext_vector_type(8))) short short8;
typedef __attribute__((ext_vector_type(4))) unsigned short ushort4v;

__device__ inline unsigned short f2bf(float x) {
    __hip_bfloat16 h = __float2bfloat16(x);
    return __builtin_bit_cast(unsigned short, h);
}
__device__ inline float bf2f(unsigned short u) {
    return __uint_as_float(((unsigned int)u) << 16);
}

__device__ inline void gridbar64(int* c) {
    __syncthreads();
    if (threadIdx.x == 0) {
        __threadfence();
        atomicAdd(c, 1);
        while (atomicAdd(c, 0) < 64) __builtin_amdgcn_s_sleep(8);
        __threadfence();
    }
    __syncthreads();
}

// ---- 1. dense partials + zero hist/cbar ----
__global__ __launch_bounds__(256) void k_densep(const float* __restrict__ latent,
                                                const float* __restrict__ Wd,
                                                float* __restrict__ pdense,
                                                int* __restrict__ hist,
                                                int* __restrict__ cbar) {
    int n0 = blockIdx.x * 32, d0 = blockIdx.y * 64;
    __shared__ float lat[8][64];
    int tid = threadIdx.x;
    if (blockIdx.y == 0) hist[blockIdx.x * 256 + tid] = 0;
    if (blockIdx.x == 0 && blockIdx.y == 0 && tid < 16) cbar[tid] = 0;
    #pragma unroll
    for (int r = 0; r < 2; ++r) {
        int i = r * 256 + tid;
        lat[i >> 6][i & 63] = latent[(i >> 6) * DDIM + d0 + (i & 63)];
    }
    __syncthreads();
    int nl = tid & 31, b = tid >> 5;
    const float* wp = Wd + (size_t)d0 * NND + n0 + nl;
    float acc = 0.f;
    #pragma unroll 8
    for (int d = 0; d < 64; ++d) acc += lat[b][d] * wp[(size_t)d * NND];
    pdense[((size_t)blockIdx.y * BSZ + b) * NND + n0 + nl] = acc;
}

// ---- 2. fused: reduce partials -> conv1 -> GAT QKV projections + edge hist ----
__global__ __launch_bounds__(64) void k_gat(const float* __restrict__ pdense,
                                            const float* __restrict__ bd,
                                            const float* __restrict__ w1,
                                            const float* __restrict__ b1,
                                            const float* __restrict__ Wq, const float* __restrict__ bq,
                                            const float* __restrict__ Wk, const float* __restrict__ bk,
                                            const float* __restrict__ Wv,
                                            const int* __restrict__ ei,
                                            float* __restrict__ Qg, float* __restrict__ Kg,
                                            float* __restrict__ Vg, int* __restrict__ hist) {
    int i = blockIdx.x * 64 + threadIdx.x;
    int b = i >> 11, n = i & (NND - 1);
    float sm = 0.f, s0 = 0.f, sp = 0.f;
    #pragma unroll
    for (int ds = 0; ds < 8; ++ds) {
        const float* p = pdense + ((size_t)ds * BSZ + b) * NND + n;
        if (n > 0) sm += p[-1];
        s0 += p[0];
        if (n < NND - 1) sp += p[1];
    }
    if (n > 0) sm += bd[n - 1];
    s0 += bd[n];
    if (n < NND - 1) sp += bd[n + 1];
    float xr[EE];
    #pragma unroll
    for (int e = 0; e < EE; ++e)
        xr[e] = sm * w1[e] + s0 * w1[EE + e] + sp * w1[2 * EE + e] + b1[e];
    #pragma unroll
    for (int j = 0; j < EE; ++j) {
        float q = bq[j], k = bk[j], v = 0.f;
        #pragma unroll
        for (int c = 0; c < EE; ++c) {
            q += xr[c] * Wq[c * EE + j];
            k += xr[c] * Wk[c * EE + j];
            v += xr[c] * Wv[c * EE + j];
        }
        Qg[(size_t)i * EE + j] = (q >= 0.f) ? q : 0.2f * q;
        Kg[(size_t)i * EE + j] = (k >= 0.f) ? k : 0.2f * k;
        Vg[(size_t)i * EE + j] = v;
    }
    #pragma unroll 4
    for (int j = 0; j < 32; ++j)
        atomicAdd(hist + ei[i + j * BNN], 1);
}

// ---- 3. exclusive prefix sum over 16384 counts ----
__global__ __launch_bounds__(1024) void k_scan(const int* __restrict__ hist,
                                               int* __restrict__ offs,
                                               int* __restrict__ cnt) {
    int tid = threadIdx.x;
    int lane = tid & 63, wv = tid >> 6;
    const int4* hp = (const int4*)(hist + tid * 16);
    int4 a = hp[0], b4 = hp[1], c4 = hp[2], d4 = hp[3];
    int h[16] = {a.x, a.y, a.z, a.w, b4.x, b4.y, b4.z, b4.w,
                 c4.x, c4.y, c4.z, c4.w, d4.x, d4.y, d4.z, d4.w};
    int mysum = 0;
    #pragma unroll
    for (int i = 0; i < 16; ++i) mysum += h[i];
    int inc = mysum;
    #pragma unroll
    for (int off = 1; off < 64; off <<= 1) {
        int u = __shfl_up(inc, off, 64);
        if (lane >= off) inc += u;
    }
    __shared__ int wtot[16];
    if (lane == 63) wtot[wv] = inc;
    __syncthreads();
    if (tid < 16) {
        int t = wtot[tid];
        #pragma unroll
        for (int off = 1; off < 16; off <<= 1) {
            int u = __shfl_up(t, off, 16);
            if (tid >= off) t += u;
        }
        wtot[tid] = t;
    }
    __syncthreads();
    int run = (wv ? wtot[wv - 1] : 0) + inc - mysum;
    #pragma unroll
    for (int i = 0; i < 16; ++i) {
        offs[tid * 16 + i] = run;
        cnt[tid * 16 + i] = run;
        run += h[i];
    }
}

// ---- 4. scatter edge columns into destination buckets ----
__global__ void k_scatter(const int* __restrict__ ei, int* __restrict__ cnt,
                          int* __restrict__ ecol) {
    int e = blockIdx.x * 256 + threadIdx.x;
    if (e >= NEDGE) return;
    int r = ei[e], c = ei[NEDGE + e];
    int pos = atomicAdd(cnt + r, 1);
    ecol[pos] = c;
}

// ---- 5. per-row gather + online softmax + aggregate ----
__global__ __launch_bounds__(256) void k_gatagg(const int* __restrict__ ecol,
                                                const int* __restrict__ offs,
                                                const int* __restrict__ hist,
                                                const float* __restrict__ Qg,
                                                const float* __restrict__ Kg,
                                                const float* __restrict__ Vg,
                                                const float* __restrict__ gbias,
                                                float* __restrict__ hg) {
    int row = __builtin_amdgcn_readfirstlane(blockIdx.x * 4 + (threadIdx.x >> 6));
    int lane = threadIdx.x & 63;
    const float* Qr = Qg + (size_t)row * EE;
    float q0 = Qr[0], q1 = Qr[1], q2 = Qr[2], q3 = Qr[3];
    float q4 = Qr[4], q5 = Qr[5], q6 = Qr[6], q7 = Qr[7];
    int beg = offs[row], deg = hist[row];
    int total = deg + 1;
    float m = -INFINITY, l = 0.f;
    float acc[EE];
    #pragma unroll
    for (int j = 0; j < EE; ++j) acc[j] = 0.f;
    for (int base = 0; base < total; base += 64) {
        int idx = base + lane;
        int c = row;
        if (idx < deg) c = ecol[beg + idx];
        const float4* K4 = (const float4*)(Kg + (size_t)c * EE);
        float4 ka = K4[0], kb = K4[1];
        float s = q0*ka.x + q1*ka.y + q2*ka.z + q3*ka.w
                + q4*kb.x + q5*kb.y + q6*kb.z + q7*kb.w;
        if (idx >= total) s = -INFINITY;
        float pm = s;
        #pragma unroll
        for (int off = 32; off > 0; off >>= 1) pm = fmaxf(pm, __shfl_xor(pm, off));
        float nm = fmaxf(m, pm);
        float scale = __expf(m - nm);
        float p = (idx < total) ? __expf(s - nm) : 0.f;
        float ps = p;
        #pragma unroll
        for (int off = 32; off > 0; off >>= 1) ps += __shfl_xor(ps, off);
        l = l * scale + ps;
        const float4* V4 = (const float4*)(Vg + (size_t)c * EE);
        float4 va = V4[0], vb = V4[1];
        float pv[EE] = {p*va.x, p*va.y, p*va.z, p*va.w, p*vb.x, p*vb.y, p*vb.z, p*vb.w};
        #pragma unroll
        for (int j = 0; j < EE; ++j) {
            float t = pv[j];
            #pragma unroll
            for (int off = 32; off > 0; off >>= 1) t += __shfl_xor(t, off);
            acc[j] = acc[j] * scale + t;
        }
        m = nm;
    }
    if (lane < EE)
        hg[(size_t)row * EE + lane] = acc[lane] / l + gbias[lane];
}

// ==== 6. midfuse: blocks 0-63 Mpart -> bar -> S+softmax ; blocks 64-239 v-conv -> FvT ====
__global__ __launch_bounds__(256) void k_midfuse(const float* __restrict__ hg,
                                                 const float* __restrict__ qw,
                                                 const float* __restrict__ qb,
                                                 unsigned short* __restrict__ FvT,
                                                 float* __restrict__ Mpart,
                                                 float* __restrict__ atT,
                                                 int* __restrict__ cbar) {
    __shared__ float smem[16064];   // 64.25 KB, aliased per role
    int bid = blockIdx.x, tid = threadIdx.x;
    if (bid >= 64) {
        // ---- v-conv role: chunk cx of 32 nodes, batch b; write FvT[b][d][s] bf16 ----
        int u = bid - 64;
        int cx = u % 22, b = u / 22;
        int n0 = 682 + cx * 32;
        float* hs = smem;                                    // 272 floats
        unsigned short* st = (unsigned short*)(smem + 272);  // 32*768 ushorts
        for (int i = tid; i < 34 * EE; i += 256) {
            int nn = n0 - 1 + (i >> 3);
            hs[i] = (nn >= 0 && nn < NND) ? hg[((size_t)b * NND + nn) * EE + (i & 7)] : 0.f;
        }
        __syncthreads();
        int dbase = n0 * 24 - DQ;
        #pragma unroll
        for (int pass = 0; pass < 2; ++pass) {
            if (pass) __syncthreads();
            float w[3][24], bias[3];
            #pragma unroll
            for (int rr = 0; rr < 3; ++rr) {
                int o = pass * 768 + rr * 256 + tid;
                bias[rr] = qb[o];
                #pragma unroll
                for (int kk = 0; kk < 24; ++kk) w[rr][kk] = qw[kk * OCC + o];
            }
            for (int nn = 0; nn < 32; ++nn) {
                const float* hv = &hs[nn * EE];
                float a0 = bias[0], a1 = bias[1], a2 = bias[2];
                #pragma unroll
                for (int kk = 0; kk < 24; ++kk) {
                    float h = hv[kk];
                    a0 += h * w[0][kk]; a1 += h * w[1][kk]; a2 += h * w[2][kk];
                }
                st[nn * 768 + tid]       = f2bf(a0);
                st[nn * 768 + tid + 256] = f2bf(a1);
                st[nn * 768 + tid + 512] = f2bf(a2);
            }
            __syncthreads();
            int l0 = pass * 32;
            #pragma unroll
            for (int it = 0; it < 24; ++it) {
                int idx4 = it * 256 + tid;          // 6144 = 768 d x 8 s-groups
                int dl = idx4 >> 3, s4 = idx4 & 7;
                int d = dbase + dl;
                if (d < 0 || d >= DQ) continue;
                int nn = dl / 24, c = dl - nn * 24;
                const unsigned short* sb = st + nn * 768 + c;
                ushort4v v4 = { sb[(s4 * 4 + 0) * 24], sb[(s4 * 4 + 1) * 24],
                                sb[(s4 * 4 + 2) * 24], sb[(s4 * 4 + 3) * 24] };
                *(ushort4v*)(FvT + ((size_t)b * DQ + d) * 64 + l0 + s4 * 4) = v4;
            }
        }
    } else {
        // ---- Mpart role ----
        int sp = bid >> 3, b = bid & 7;
        int nq0 = sp * 86;
        float* hq = smem;            // [88][8]
        float* hk = smem + 704;      // [90][8]
        for (int i = tid; i < 88 * EE; i += 256) {
            int r = nq0 - 1 + (i >> 3);
            hq[i] = (r >= 0 && r < NND) ? hg[((size_t)b * NND + r) * EE + (i & 7)] : 0.f;
        }
        for (int i = tid; i < 90 * EE; i += 256) {
            int r = nq0 + 1364 + (i >> 3);
            hk[i] = (r < NND) ? hg[((size_t)b * NND + r) * EE + (i & 7)] : 0.f;
        }
        __syncthreads();
        int cnt1 = 683 - nq0; if (cnt1 > 86) cnt1 = 86; if (cnt1 < 0) cnt1 = 0;
        int cnt2 = 682 - nq0; if (cnt2 > 86) cnt2 = 86; if (cnt2 < 0) cnt2 = 0;
        for (int idx = tid; idx < 1250; idx += 256) {
            int mm = idx / 625, p = idx - (idx / 625) * 625;
            int i = p / 25, j = p - (p / 25) * 25;
            int cnt = mm ? cnt2 : cnt1;
            int qi = i >> 3, qe = i & 7;
            int kj = (j >> 3) + mm, ke = j & 7;
            float acc = 0.f;
            if (i < 24 && j < 24) {
                for (int nl = 0; nl < cnt; ++nl)
                    acc += hq[(nl + qi) * EE + qe] * hk[(nl + kj) * EE + ke];
            } else if (i < 24) {
                for (int nl = 0; nl < cnt; ++nl) acc += hq[(nl + qi) * EE + qe];
            } else if (j < 24) {
                for (int nl = 0; nl < cnt; ++nl) acc += hk[(nl + kj) * EE + ke];
            } else {
                acc = (float)cnt;
            }
            Mpart[((size_t)(sp * 8 + b)) * 1250 + idx] = acc;
        }
        gridbar64(cbar);
        // ---- S contraction + softmax role: t = bid ----
        int t = bid;
        float* Ms = smem;            // [8][1250]
        float* As = smem + 10000;    // [25*24]
        float* T1 = smem + 10600;    // [8][600]
        for (int idx = tid; idx < 10000; idx += 256) {
            int b2 = idx / 1250, r = idx - (idx / 1250) * 1250;
            float s = 0.f;
            #pragma unroll
            for (int sp2 = 0; sp2 < 8; ++sp2)
                s += Mpart[((size_t)(sp2 * 8 + b2)) * 1250 + r];
            Ms[b2 * 1250 + r] = s;
        }
        for (int idx = tid; idx < 600; idx += 256) {
            int i = idx / 24, c = idx - (idx / 24) * 24;
            As[idx] = (i < 24) ? qw[i * OCC + t * 24 + c] : qb[t * 24 + c];
        }
        __syncthreads();
        for (int idx = tid; idx < 4800; idx += 256) {
            int b2 = idx / 600, rem = idx - (idx / 600) * 600;
            int j = rem / 24, c = rem - (rem / 24) * 24;
            int mo = (c < 16) ? 0 : 625;
            float acc = 0.f;
            #pragma unroll 5
            for (int i = 0; i < 25; ++i)
                acc += Ms[b2 * 1250 + mo + i * 25 + j] * As[i * 24 + c];
            T1[b2 * 600 + j * 24 + c] = acc;
        }
        __syncthreads();
        int s = tid & 63, bg = tid >> 6;
        float acc0 = 0.f, acc1 = 0.f;
        for (int j = 0; j < 25; ++j) {
            float Bv[24];
            const float* bp = (j < 24) ? (qw + (size_t)j * OCC + s * 24) : (qb + s * 24);
            #pragma unroll
            for (int r = 0; r < 6; ++r) {
                float4 v = *(const float4*)(bp + r * 4);
                Bv[r*4+0]=v.x; Bv[r*4+1]=v.y; Bv[r*4+2]=v.z; Bv[r*4+3]=v.w;
            }
            const float* t1a = &T1[bg * 600 + j * 24];
            const float* t1b = &T1[(bg + 4) * 600 + j * 24];
            #pragma unroll
            for (int c = 0; c < 16; ++c) {
                acc0 += t1a[c] * Bv[8 + c];
                acc1 += t1b[c] * Bv[8 + c];
            }
            #pragma unroll
            for (int c = 16; c < 24; ++c) {
                acc0 += t1a[c] * Bv[c - 16];
                acc1 += t1b[c] * Bv[c - 16];
            }
        }
        #pragma unroll
        for (int r = 0; r < 2; ++r) {
            int b2 = bg + r * 4;
            float v = r ? acc1 : acc0;
            float m = v;
            #pragma unroll
            for (int off = 32; off > 0; off >>= 1) m = fmaxf(m, __shfl_xor(m, off));
            float e = __expf(v - m);
            float sum = e;
            #pragma unroll
            for (int off = 32; off > 0; off >>= 1) sum += __shfl_xor(sum, off);
            atT[((size_t)b2 * LLH + s) * LLH + t] = e / sum;
        }
    }
}

// ---- 7. out[b][t][d] = sum_s atT[b][s][t] * v[s][d]; FvT coalesced staging ----
__global__ __launch_bounds__(256) void k_attnV(const unsigned short* __restrict__ FvT,
                                               const float* __restrict__ atT,
                                               float* __restrict__ out) {
    int b = blockIdx.y;
    int d0 = blockIdx.x * 64;
    int tid = threadIdx.x;
    __shared__ float vtf[64][65];
    #pragma unroll
    for (int r = 0; r < 2; ++r) {
        int idx = r * 256 + tid;               // 512 = 64 d x 8 groups
        int dl = idx >> 3, g = idx & 7;
        short8 v = *(const short8*)(FvT + ((size_t)b * DQ + d0 + dl) * 64 + g * 8);
        #pragma unroll
        for (int j = 0; j < 8; ++j)
            vtf[dl][g * 8 + j] = bf2f((unsigned short)v[j]);
    }
    __syncthreads();
    int lane = tid & 63;
    int t0 = __builtin_amdgcn_readfirstlane((tid >> 6) * 16);
    const float* arow = atT + (size_t)b * LLH * LLH + t0;
    float acc[16];
    #pragma unroll
    for (int tt = 0; tt < 16; ++tt) acc[tt] = 0.f;
    #pragma unroll 4
    for (int s = 0; s < LLH; ++s) {
        float vv = vtf[lane][s];
        #pragma unroll
        for (int tt = 0; tt < 16; ++tt)
            acc[tt] += arow[s * LLH + tt] * vv;   // wave-uniform -> scalar loads
    }
    float* ob = out + ((size_t)b * LLH + t0) * DQ + d0 + lane;
    #pragma unroll
    for (int tt = 0; tt < 16; ++tt) ob[(size_t)tt * DQ] = acc[tt];
}

extern "C" void kernel_launch(void* const* d_in, const int* in_sizes, int n_in,
                              void* d_out, int out_size, void* d_ws, size_t ws_size,
                              hipStream_t stream) {
    (void)in_sizes; (void)n_in; (void)out_size; (void)ws_size;
    const float* latent = (const float*)d_in[0];
    const int*   ei     = (const int*)d_in[1];
    const float* Wd     = (const float*)d_in[2];
    const float* bd     = (const float*)d_in[3];
    const float* w1     = (const float*)d_in[4];
    const float* b1     = (const float*)d_in[5];
    const float* Wq     = (const float*)d_in[6];
    const float* bq     = (const float*)d_in[7];
    const float* Wk     = (const float*)d_in[8];
    const float* bk     = (const float*)d_in[9];
    const float* Wv     = (const float*)d_in[10];
    const float* gbias  = (const float*)d_in[11];
    const float* qw     = (const float*)d_in[12];
    const float* qb     = (const float*)d_in[13];
    float* out = (float*)d_out;

    float* ws     = (float*)d_ws;
    float* pdense = ws;                          // 131072
    float* Qg     = pdense + 64 * NND;           // 131072
    float* Kg     = Qg + BNN * EE;               // 131072
    float* Vg     = Kg + BNN * EE;               // 131072
    float* hg     = Vg + BNN * EE;               // 131072
    int*   hist   = (int*)(hg + BNN * EE);       // 16384
    int*   offs   = hist + BNN;                  // 16384
    int*   cnt    = offs + BNN;                  // 16384
    int*   ecol   = cnt + BNN;                   // 524288
    int*   cbar   = ecol + NEDGE;                // 16
    float* Mp     = (float*)(cbar + 16);         // 80000
    float* atT    = Mp + 80000;                  // 32768
    unsigned short* FvT = (unsigned short*)(atT + BSZ * LLH * LLH);  // 8*16384*64 bf16 (~16.8 MB)

    k_densep<<<dim3(64, 8), dim3(256), 0, stream>>>(latent, Wd, pdense, hist, cbar);
    k_gat<<<dim3(256), dim3(64), 0, stream>>>(pdense, bd, w1, b1, Wq, bq, Wk, bk, Wv,
                                              ei, Qg, Kg, Vg, hist);
    k_scan<<<dim3(1), dim3(1024), 0, stream>>>(hist, offs, cnt);
    k_scatter<<<dim3(NEDGE / 256), dim3(256), 0, stream>>>(ei, cnt, ecol);
    k_gatagg<<<dim3(BNN / 4), dim3(256), 0, stream>>>(ecol, offs, hist,
                                                      Qg, Kg, Vg, gbias, hg);
    k_midfuse<<<dim3(240), dim3(256), 0, stream>>>(hg, qw, qb, FvT, Mp, atT, cbar);
    k_attnV<<<dim3(256, 8), dim3(256), 0, stream>>>(FvT, atT, out);
}